// Round 2
// baseline (4658.706 us; speedup 1.0000x reference)
//
#include <hip/hip_runtime.h>
#include <math.h>

#define N_NODES 200000
#define N_EDGES 3200000
#define M_SEL   100000
#define NEX     32
#define NT      11
#define CH      32
#define HID     1024
#define NL      8
#define BN_EPS  1e-5f

// bf16 helpers (RNE), manual to avoid API friction
__device__ __forceinline__ unsigned bf16_bits(float f) {
  unsigned u = __float_as_uint(f);
  return (u + 0x7fffu + ((u >> 16) & 1u)) >> 16;
}
__device__ __forceinline__ unsigned pack_bf2(float lo, float hi) {
  return bf16_bits(lo) | (bf16_bits(hi) << 16);
}
#define BF_LO(u) __uint_as_float((u) << 16)
#define BF_HI(u) __uint_as_float((u) & 0xffff0000u)

// ---------------------------------------------------------------------------
// CSR build: histogram -> scan -> scatter
// ---------------------------------------------------------------------------
__global__ void __launch_bounds__(256) hist_kernel(
    const int* __restrict__ src, const int* __restrict__ dst,
    int* __restrict__ deg_in, int* __restrict__ deg_out) {
  int e = blockIdx.x * blockDim.x + threadIdx.x;
  if (e < N_EDGES) {
    atomicAdd(&deg_in[dst[e]], 1);
    atomicAdd(&deg_out[src[e]], 1);
  }
}

__global__ void __launch_bounds__(1024) scan_kernel(
    const int* __restrict__ degA, int* __restrict__ offA, int* __restrict__ curA,
    const int* __restrict__ degB, int* __restrict__ offB, int* __restrict__ curB) {
  const int n = N_NODES;
  const int* deg = blockIdx.x ? degB : degA;
  int* off = blockIdx.x ? offB : offA;
  int* cur = blockIdx.x ? curB : curA;
  __shared__ int wsum[16];
  int tid = threadIdx.x;
  int lane = tid & 63, wid = tid >> 6;
  int carry = 0;
  if (tid == 0) off[0] = 0;
  for (int base = 0; base < n; base += 1024) {
    int idx = base + tid;
    int v0 = (idx < n) ? deg[idx] : 0;
    int v = v0;
#pragma unroll
    for (int o = 1; o < 64; o <<= 1) {
      int t = __shfl_up(v, o);
      if (lane >= o) v += t;
    }
    if (lane == 63) wsum[wid] = v;
    __syncthreads();
    if (tid < 16) {
      int t = wsum[tid];
#pragma unroll
      for (int o = 1; o < 16; o <<= 1) {
        int u = __shfl_up(t, o);
        if (tid >= o) t += u;
      }
      wsum[tid] = t;
    }
    __syncthreads();
    int add = carry + (wid ? wsum[wid - 1] : 0);
    int incl = v + add;
    if (idx < n) { off[idx + 1] = incl; cur[idx] = incl - v0; }
    int tot = wsum[15];
    __syncthreads();
    carry += tot;
  }
}

__global__ void __launch_bounds__(256) scatter_kernel(
    const int* __restrict__ src, const int* __restrict__ dst,
    int* __restrict__ cur_in, int* __restrict__ cur_out,
    int* __restrict__ csr_in, int* __restrict__ csr_out) {
  int e = blockIdx.x * blockDim.x + threadIdx.x;
  if (e < N_EDGES) {
    int s = src[e], d = dst[e];
    int p = atomicAdd(&cur_in[d], 1);  csr_in[p] = s;
    int q = atomicAdd(&cur_out[s], 1); csr_out[q] = d;
  }
}

// ---------------------------------------------------------------------------
// A0: x0 = emb[nodes]; y = x0 @ [w0_out | w0_back]  -> bf16 y
// ---------------------------------------------------------------------------
__global__ void __launch_bounds__(256) emb_mm_kernel(
    const int* __restrict__ nodes, const float* __restrict__ emb,
    const float* __restrict__ w_out, const float* __restrict__ w_back,
    unsigned short* __restrict__ y) {
  __shared__ float W[CH][CH];
  __shared__ float Esh[NT * CH];
  int tid = threadIdx.x;
  for (int t = tid; t < CH * CH; t += blockDim.x) {
    int k = t >> 5, j = t & 31;
    W[k][j] = (j < 16) ? w_out[k * 16 + j] : w_back[k * 16 + j - 16];
  }
  for (int t = tid; t < NT * CH; t += blockDim.x) Esh[t] = emb[t];
  __syncthreads();
  int i = blockIdx.x * blockDim.x + tid;
  if (i >= N_NODES) return;
  int tn = nodes[i];
  float v[CH];
#pragma unroll
  for (int k = 0; k < CH; k++) v[k] = Esh[tn * CH + k];
  float acc[CH];
#pragma unroll
  for (int j = 0; j < CH; j++) acc[j] = 0.f;
#pragma unroll
  for (int k = 0; k < CH; k++) {
    float vk = v[k];
#pragma unroll
    for (int j = 0; j < CH; j++) acc[j] += vk * W[k][j];
  }
  uint4* yp = (uint4*)(y + (size_t)i * CH);
#pragma unroll
  for (int q = 0; q < 4; q++) {
    uint4 t;
    t.x = pack_bf2(acc[8 * q + 0], acc[8 * q + 1]);
    t.y = pack_bf2(acc[8 * q + 2], acc[8 * q + 3]);
    t.z = pack_bf2(acc[8 * q + 4], acc[8 * q + 5]);
    t.w = pack_bf2(acc[8 * q + 6], acc[8 * q + 7]);
    yp[q] = t;
  }
}

// ---------------------------------------------------------------------------
// A: y = relu(bn(x; stats,g,b)) @ [w_out | w_back]  -> bf16 y
// ---------------------------------------------------------------------------
__global__ void __launch_bounds__(256) bn_relu_mm_kernel(
    const float* __restrict__ xin, const float* __restrict__ stats,
    const float* __restrict__ gamma, const float* __restrict__ beta,
    const float* __restrict__ w_out, const float* __restrict__ w_back,
    unsigned short* __restrict__ y) {
  __shared__ float W[CH][CH];
  __shared__ float sc[CH], sh[CH];
  int tid = threadIdx.x;
  for (int t = tid; t < CH * CH; t += blockDim.x) {
    int k = t >> 5, j = t & 31;
    W[k][j] = (j < 16) ? w_out[k * 16 + j] : w_back[k * 16 + j - 16];
  }
  if (tid < CH) {
    float m  = stats[tid] * (1.0f / N_NODES);
    float s2 = stats[CH + tid] * (1.0f / N_NODES);
    float var = s2 - m * m;
    float scale = gamma[tid] * rsqrtf(var + BN_EPS);
    sc[tid] = scale;
    sh[tid] = beta[tid] - m * scale;
  }
  __syncthreads();
  int i = blockIdx.x * blockDim.x + tid;
  if (i >= N_NODES) return;
  const float4* xp = (const float4*)(xin + (size_t)i * CH);
  float v[CH];
#pragma unroll
  for (int q = 0; q < 8; q++) {
    float4 t = xp[q];
    v[4 * q + 0] = fmaxf(t.x * sc[4 * q + 0] + sh[4 * q + 0], 0.f);
    v[4 * q + 1] = fmaxf(t.y * sc[4 * q + 1] + sh[4 * q + 1], 0.f);
    v[4 * q + 2] = fmaxf(t.z * sc[4 * q + 2] + sh[4 * q + 2], 0.f);
    v[4 * q + 3] = fmaxf(t.w * sc[4 * q + 3] + sh[4 * q + 3], 0.f);
  }
  float acc[CH];
#pragma unroll
  for (int j = 0; j < CH; j++) acc[j] = 0.f;
#pragma unroll
  for (int k = 0; k < CH; k++) {
    float vk = v[k];
#pragma unroll
    for (int j = 0; j < CH; j++) acc[j] += vk * W[k][j];
  }
  uint4* yp = (uint4*)(y + (size_t)i * CH);
#pragma unroll
  for (int q = 0; q < 4; q++) {
    uint4 t;
    t.x = pack_bf2(acc[8 * q + 0], acc[8 * q + 1]);
    t.y = pack_bf2(acc[8 * q + 2], acc[8 * q + 3]);
    t.z = pack_bf2(acc[8 * q + 4], acc[8 * q + 5]);
    t.w = pack_bf2(acc[8 * q + 6], acc[8 * q + 7]);
    yp[q] = t;
  }
}

// ---------------------------------------------------------------------------
// B: aggregation over bf16 y, fp32 accumulate. 2 threads per (node,direction)
// job, 8 channels each (one uint4 = 8 bf16 per edge per thread).
// Grid exact: 2N jobs * 2 threads = 800000 = 3125 blocks * 256.
// N % 32 == 0 -> each wave is direction-uniform.
// ---------------------------------------------------------------------------
__global__ void __launch_bounds__(256) agg_kernel(
    const unsigned short* __restrict__ y, const float* __restrict__ xres,
    float* __restrict__ out,
    const int* __restrict__ off_in, const int* __restrict__ csr_in,
    const int* __restrict__ off_out, const int* __restrict__ csr_out,
    float* __restrict__ stats) {
  __shared__ float ssum[CH], sssq[CH];
  int tid = threadIdx.x;
  if (tid < CH) { ssum[tid] = 0.f; sssq[tid] = 0.f; }
  __syncthreads();
  int t = blockIdx.x * 256 + tid;
  int q = t & 1;       // 8-channel group within direction
  int j = t >> 1;      // job in [0, 2N)
  int half = (j >= N_NODES) ? 1 : 0;
  int i = half ? j - N_NODES : j;
  const int* off = half ? off_out : off_in;
  const int* csr = half ? csr_out : csr_in;
  int lo = off[i], hi = off[i + 1];
  int base = half * 16 + q * 8;  // channel base
  float acc[8];
#pragma unroll
  for (int k = 0; k < 8; k++) acc[k] = 0.f;
  for (int e = lo; e < hi; e++) {
    int nb = csr[e];
    uint4 p = *(const uint4*)(y + (size_t)nb * CH + base);
    acc[0] += BF_LO(p.x); acc[1] += BF_HI(p.x);
    acc[2] += BF_LO(p.y); acc[3] += BF_HI(p.y);
    acc[4] += BF_LO(p.z); acc[5] += BF_HI(p.z);
    acc[6] += BF_LO(p.w); acc[7] += BF_HI(p.w);
  }
  if (xres) {
    const float4* rp = (const float4*)(xres + (size_t)i * CH + base);
    float4 r0 = rp[0], r1 = rp[1];
    acc[0] += r0.x; acc[1] += r0.y; acc[2] += r0.z; acc[3] += r0.w;
    acc[4] += r1.x; acc[5] += r1.y; acc[6] += r1.z; acc[7] += r1.w;
  }
  float4* op = (float4*)(out + (size_t)i * CH + base);
  op[0] = make_float4(acc[0], acc[1], acc[2], acc[3]);
  op[1] = make_float4(acc[4], acc[5], acc[6], acc[7]);
  if (stats) {
    float sq[8];
#pragma unroll
    for (int k = 0; k < 8; k++) sq[k] = acc[k] * acc[k];
    // reduce across the 32 jobs in this wave, preserving lane parity (q)
#pragma unroll
    for (int o = 32; o >= 2; o >>= 1) {
#pragma unroll
      for (int k = 0; k < 8; k++) {
        acc[k] += __shfl_down(acc[k], o);
        sq[k]  += __shfl_down(sq[k], o);
      }
    }
    if ((tid & 63) < 2) {  // lanes 0 (q=0) and 1 (q=1) hold totals
#pragma unroll
      for (int k = 0; k < 8; k++) {
        atomicAdd(&ssum[base + k], acc[k]);
        atomicAdd(&sssq[base + k], sq[k]);
      }
    }
    __syncthreads();
    if (tid < CH) {
      atomicAdd(&stats[tid], ssum[tid]);
      atomicAdd(&stats[CH + tid], sssq[tid]);
    }
  }
}

// ---------------------------------------------------------------------------
// MLP head (x stays fp32)
// ---------------------------------------------------------------------------
__global__ void __launch_bounds__(256) score_kernel(
    const float* __restrict__ x, const int* __restrict__ indices,
    const int* __restrict__ assignment,
    const float* __restrict__ wh, const float* __restrict__ bh,
    const float* __restrict__ wo, const float* __restrict__ bo,
    float* __restrict__ s, int* __restrict__ seg) {
  __shared__ __align__(16) float s_wh[256][36];
  __shared__ float s_wo[256];
  __shared__ float s_bh[256];
  int tid = threadIdx.x;
  int m = blockIdx.x * 256 + tid;
  bool valid = m < M_SEL;
  float a[CH];
  int idx = 0;
  if (valid) {
    idx = indices[m];
    const float4* xp = (const float4*)(x + (size_t)idx * CH);
#pragma unroll
    for (int q = 0; q < 8; q++) {
      float4 t = xp[q];
      a[4 * q + 0] = fmaxf(t.x, 0.f); a[4 * q + 1] = fmaxf(t.y, 0.f);
      a[4 * q + 2] = fmaxf(t.z, 0.f); a[4 * q + 3] = fmaxf(t.w, 0.f);
    }
  }
  float sacc = 0.f;
  for (int t0 = 0; t0 < HID; t0 += 256) {
    for (int u = tid; u < CH * 256; u += 256) {
      int k = u >> 8, jj = u & 255;
      s_wh[jj][k] = wh[(size_t)k * HID + t0 + jj];
    }
    s_wo[tid] = wo[t0 + tid];
    s_bh[tid] = bh[t0 + tid];
    __syncthreads();
    if (valid) {
      for (int jj = 0; jj < 256; jj++) {
        float h = s_bh[jj];
        const float4* wp = (const float4*)&s_wh[jj][0];
#pragma unroll
        for (int q = 0; q < 8; q++) {
          float4 w = wp[q];
          h += a[4 * q] * w.x + a[4 * q + 1] * w.y + a[4 * q + 2] * w.z + a[4 * q + 3] * w.w;
        }
        sacc += fmaxf(h, 0.f) * s_wo[jj];
      }
    }
    __syncthreads();
  }
  if (valid) {
    s[m] = sacc + bo[0];
    seg[m] = assignment[idx];
  }
}

// ---------------------------------------------------------------------------
// Segmented log-softmax (seg sorted; one block per segment)
// ---------------------------------------------------------------------------
__device__ __forceinline__ int lower_bound_dev(const int* a, int n, int key) {
  int lo = 0, hi = n;
  while (lo < hi) { int mid = (lo + hi) >> 1; if (a[mid] < key) lo = mid + 1; else hi = mid; }
  return lo;
}

__global__ void __launch_bounds__(256) logsoftmax_kernel(
    const float* __restrict__ s, const int* __restrict__ seg, float* __restrict__ out) {
  __shared__ float red[256];
  __shared__ int bounds[2];
  int tid = threadIdx.x;
  int b = blockIdx.x;
  if (tid == 0) {
    bounds[0] = lower_bound_dev(seg, M_SEL, b);
    bounds[1] = lower_bound_dev(seg, M_SEL, b + 1);
  }
  __syncthreads();
  int lo = bounds[0], hi = bounds[1];
  float mx = -INFINITY;
  for (int i = lo + tid; i < hi; i += 256) mx = fmaxf(mx, s[i]);
  red[tid] = mx; __syncthreads();
  for (int o = 128; o > 0; o >>= 1) { if (tid < o) red[tid] = fmaxf(red[tid], red[tid + o]); __syncthreads(); }
  float mxv = red[0];
  __syncthreads();
  float sum = 0.f;
  for (int i = lo + tid; i < hi; i += 256) sum += expf(s[i] - mxv);
  red[tid] = sum; __syncthreads();
  for (int o = 128; o > 0; o >>= 1) { if (tid < o) red[tid] += red[tid + o]; __syncthreads(); }
  float lse = logf(red[0]);
  for (int i = lo + tid; i < hi; i += 256) out[i] = (s[i] - mxv) - lse;
}

// ---------------------------------------------------------------------------
extern "C" void kernel_launch(void* const* d_in, const int* in_sizes, int n_in,
                              void* d_out, int out_size, void* d_ws, size_t ws_size,
                              hipStream_t stream) {
  const int*   assignment = (const int*)d_in[1];
  const int*   nodes      = (const int*)d_in[2];
  const int*   src        = (const int*)d_in[3];
  const int*   dst        = (const int*)d_in[4];
  const int*   indices    = (const int*)d_in[5];
  const float* emb        = (const float*)d_in[6];
  const float* w0_out     = (const float*)d_in[7];
  const float* w0_back    = (const float*)d_in[8];
  const float* bn1_gamma  = (const float*)d_in[9];
  const float* bn1_beta   = (const float*)d_in[10];
  const float* w1_out     = (const float*)d_in[11];
  const float* w1_back    = (const float*)d_in[12];
  const float* bn2_gamma  = (const float*)d_in[13];
  const float* bn2_beta   = (const float*)d_in[14];
  const float* w2_out     = (const float*)d_in[15];
  const float* w2_back    = (const float*)d_in[16];
  const float* wh         = (const float*)d_in[17];
  const float* bh         = (const float*)d_in[18];
  const float* wo         = (const float*)d_in[19];
  const float* bo         = (const float*)d_in[20];
  float* out = (float*)d_out;

  char* ws = (char*)d_ws;
  size_t off = 0;
  auto alloc = [&](size_t bytes) {
    char* p = ws + off;
    off = (off + bytes + 255) & ~(size_t)255;
    return p;
  };
  int* deg_in  = (int*)alloc((size_t)2 * N_NODES * 4); int* deg_out = deg_in + N_NODES;
  int* cur_in  = (int*)alloc((size_t)2 * N_NODES * 4); int* cur_out = cur_in + N_NODES;
  int* off_in  = (int*)alloc((size_t)(N_NODES + 1) * 4);
  int* off_out = (int*)alloc((size_t)(N_NODES + 1) * 4);
  float* stats = (float*)alloc((size_t)16 * 64 * 4);
  int* csr_in  = (int*)alloc((size_t)N_EDGES * 4);
  int* csr_out = (int*)alloc((size_t)N_EDGES * 4);
  unsigned short* yb = (unsigned short*)alloc((size_t)N_NODES * CH * 2);  // bf16
  float* xb = (float*)alloc((size_t)N_NODES * CH * 4);
  float* hb = (float*)alloc((size_t)N_NODES * CH * 4);
  float* sb = (float*)alloc((size_t)M_SEL * 4);
  int* segb = (int*)alloc((size_t)M_SEL * 4);

  hipMemsetAsync(deg_in, 0, (size_t)2 * N_NODES * 4, stream);
  hipMemsetAsync(stats, 0, (size_t)16 * 64 * 4, stream);

  hist_kernel<<<N_EDGES / 256, 256, 0, stream>>>(src, dst, deg_in, deg_out);
  scan_kernel<<<2, 1024, 0, stream>>>(deg_in, off_in, cur_in, deg_out, off_out, cur_out);
  scatter_kernel<<<N_EDGES / 256, 256, 0, stream>>>(src, dst, cur_in, cur_out, csr_in, csr_out);

  const int gA = (N_NODES + 255) / 256;
  const int gB = (2 * N_NODES * 2) / 256;  // 3125 blocks, exact
  emb_mm_kernel<<<gA, 256, 0, stream>>>(nodes, emb, w0_out, w0_back, yb);
  agg_kernel<<<gB, 256, 0, stream>>>(yb, nullptr, xb, off_in, csr_in, off_out, csr_out,
                                     stats + 0 * 64);
  for (int l = 0; l < NL; l++) {
    bn_relu_mm_kernel<<<gA, 256, 0, stream>>>(xb, stats + (2 * l) * 64,
                                              bn1_gamma + l * CH, bn1_beta + l * CH,
                                              w1_out + l * CH * 16, w1_back + l * CH * 16, yb);
    agg_kernel<<<gB, 256, 0, stream>>>(yb, nullptr, hb, off_in, csr_in, off_out, csr_out,
                                       stats + (2 * l + 1) * 64);
    bn_relu_mm_kernel<<<gA, 256, 0, stream>>>(hb, stats + (2 * l + 1) * 64,
                                              bn2_gamma + l * CH, bn2_beta + l * CH,
                                              w2_out + l * CH * 16, w2_back + l * CH * 16, yb);
    agg_kernel<<<gB, 256, 0, stream>>>(yb, xb, xb, off_in, csr_in, off_out, csr_out,
                                       (l < NL - 1) ? (stats + (2 * l + 2) * 64) : nullptr);
  }
  score_kernel<<<(M_SEL + 255) / 256, 256, 0, stream>>>(xb, indices, assignment,
                                                        wh, bh, wo, bo, sb, segb);
  logsoftmax_kernel<<<NEX, 256, 0, stream>>>(sb, segb, out);
}

// Round 3
// 3944.152 us; speedup vs baseline: 1.1812x; 1.1812x over previous
//
#include <hip/hip_runtime.h>
#include <math.h>

#define N_NODES 200000
#define N_EDGES 3200000
#define M_SEL   100000
#define NEX     32
#define NT      11
#define CH      32
#define HID     1024
#define NL      8
#define BN_EPS  1e-5f

// bf16 helpers (RNE)
__device__ __forceinline__ unsigned bf16_bits(float f) {
  unsigned u = __float_as_uint(f);
  return (u + 0x7fffu + ((u >> 16) & 1u)) >> 16;
}
__device__ __forceinline__ unsigned pack_bf2(float lo, float hi) {
  return bf16_bits(lo) | (bf16_bits(hi) << 16);
}
#define BF_LO(u) __uint_as_float((u) << 16)
#define BF_HI(u) __uint_as_float((u) & 0xffff0000u)

// ---------------------------------------------------------------------------
// CSR build: histogram -> scan -> scatter
// ---------------------------------------------------------------------------
__global__ void __launch_bounds__(256) hist_kernel(
    const int* __restrict__ src, const int* __restrict__ dst,
    int* __restrict__ deg_in, int* __restrict__ deg_out) {
  int e = blockIdx.x * blockDim.x + threadIdx.x;
  if (e < N_EDGES) {
    atomicAdd(&deg_in[dst[e]], 1);
    atomicAdd(&deg_out[src[e]], 1);
  }
}

__global__ void __launch_bounds__(1024) scan_kernel(
    const int* __restrict__ degA, int* __restrict__ offA, int* __restrict__ curA,
    const int* __restrict__ degB, int* __restrict__ offB, int* __restrict__ curB) {
  const int n = N_NODES;
  const int* deg = blockIdx.x ? degB : degA;
  int* off = blockIdx.x ? offB : offA;
  int* cur = blockIdx.x ? curB : curA;
  __shared__ int wsum[16];
  int tid = threadIdx.x;
  int lane = tid & 63, wid = tid >> 6;
  int carry = 0;
  if (tid == 0) off[0] = 0;
  for (int base = 0; base < n; base += 1024) {
    int idx = base + tid;
    int v0 = (idx < n) ? deg[idx] : 0;
    int v = v0;
#pragma unroll
    for (int o = 1; o < 64; o <<= 1) {
      int t = __shfl_up(v, o);
      if (lane >= o) v += t;
    }
    if (lane == 63) wsum[wid] = v;
    __syncthreads();
    if (tid < 16) {
      int t = wsum[tid];
#pragma unroll
      for (int o = 1; o < 16; o <<= 1) {
        int u = __shfl_up(t, o);
        if (tid >= o) t += u;
      }
      wsum[tid] = t;
    }
    __syncthreads();
    int add = carry + (wid ? wsum[wid - 1] : 0);
    int incl = v + add;
    if (idx < n) { off[idx + 1] = incl; cur[idx] = incl - v0; }
    int tot = wsum[15];
    __syncthreads();
    carry += tot;
  }
}

__global__ void __launch_bounds__(256) scatter_kernel(
    const int* __restrict__ src, const int* __restrict__ dst,
    int* __restrict__ cur_in, int* __restrict__ cur_out,
    int* __restrict__ csr_in, int* __restrict__ csr_out) {
  int e = blockIdx.x * blockDim.x + threadIdx.x;
  if (e < N_EDGES) {
    int s = src[e], d = dst[e];
    int p = atomicAdd(&cur_in[d], 1);  csr_in[p] = s;
    int q = atomicAdd(&cur_out[s], 1); csr_out[q] = d;
  }
}

// ---------------------------------------------------------------------------
// Pack 32 fp32 acc channels into split bf16 arrays (16 ch each, 32 B rows)
// ---------------------------------------------------------------------------
__device__ __forceinline__ void store_split(unsigned short* y_out,
                                            unsigned short* y_back,
                                            int i, const float* acc) {
  uint4 t0, t1;
  t0.x = pack_bf2(acc[0], acc[1]);   t0.y = pack_bf2(acc[2], acc[3]);
  t0.z = pack_bf2(acc[4], acc[5]);   t0.w = pack_bf2(acc[6], acc[7]);
  t1.x = pack_bf2(acc[8], acc[9]);   t1.y = pack_bf2(acc[10], acc[11]);
  t1.z = pack_bf2(acc[12], acc[13]); t1.w = pack_bf2(acc[14], acc[15]);
  uint4* po = (uint4*)(y_out + (size_t)i * 16);
  po[0] = t0; po[1] = t1;
  t0.x = pack_bf2(acc[16], acc[17]); t0.y = pack_bf2(acc[18], acc[19]);
  t0.z = pack_bf2(acc[20], acc[21]); t0.w = pack_bf2(acc[22], acc[23]);
  t1.x = pack_bf2(acc[24], acc[25]); t1.y = pack_bf2(acc[26], acc[27]);
  t1.z = pack_bf2(acc[28], acc[29]); t1.w = pack_bf2(acc[30], acc[31]);
  uint4* pb = (uint4*)(y_back + (size_t)i * 16);
  pb[0] = t0; pb[1] = t1;
}

// ---------------------------------------------------------------------------
// A0: x0 = emb[nodes]; y = x0 @ [w0_out | w0_back]  -> split bf16
// ---------------------------------------------------------------------------
__global__ void __launch_bounds__(256) emb_mm_kernel(
    const int* __restrict__ nodes, const float* __restrict__ emb,
    const float* __restrict__ w_out, const float* __restrict__ w_back,
    unsigned short* __restrict__ y_out, unsigned short* __restrict__ y_back) {
  __shared__ float W[CH][CH];
  __shared__ float Esh[NT * CH];
  int tid = threadIdx.x;
  for (int t = tid; t < CH * CH; t += blockDim.x) {
    int k = t >> 5, j = t & 31;
    W[k][j] = (j < 16) ? w_out[k * 16 + j] : w_back[k * 16 + j - 16];
  }
  for (int t = tid; t < NT * CH; t += blockDim.x) Esh[t] = emb[t];
  __syncthreads();
  int i = blockIdx.x * blockDim.x + tid;
  if (i >= N_NODES) return;
  int tn = nodes[i];
  float v[CH];
#pragma unroll
  for (int k = 0; k < CH; k++) v[k] = Esh[tn * CH + k];
  float acc[CH];
#pragma unroll
  for (int j = 0; j < CH; j++) acc[j] = 0.f;
#pragma unroll
  for (int k = 0; k < CH; k++) {
    float vk = v[k];
#pragma unroll
    for (int j = 0; j < CH; j++) acc[j] += vk * W[k][j];
  }
  store_split(y_out, y_back, i, acc);
}

// ---------------------------------------------------------------------------
// A: y = relu(bn(x; stats,g,b)) @ [w_out | w_back]  -> split bf16
// ---------------------------------------------------------------------------
__global__ void __launch_bounds__(256) bn_relu_mm_kernel(
    const float* __restrict__ xin, const float* __restrict__ stats,
    const float* __restrict__ gamma, const float* __restrict__ beta,
    const float* __restrict__ w_out, const float* __restrict__ w_back,
    unsigned short* __restrict__ y_out, unsigned short* __restrict__ y_back) {
  __shared__ float W[CH][CH];
  __shared__ float sc[CH], sh[CH];
  int tid = threadIdx.x;
  for (int t = tid; t < CH * CH; t += blockDim.x) {
    int k = t >> 5, j = t & 31;
    W[k][j] = (j < 16) ? w_out[k * 16 + j] : w_back[k * 16 + j - 16];
  }
  if (tid < CH) {
    float m  = stats[tid] * (1.0f / N_NODES);
    float s2 = stats[CH + tid] * (1.0f / N_NODES);
    float var = s2 - m * m;
    float scale = gamma[tid] * rsqrtf(var + BN_EPS);
    sc[tid] = scale;
    sh[tid] = beta[tid] - m * scale;
  }
  __syncthreads();
  int i = blockIdx.x * blockDim.x + tid;
  if (i >= N_NODES) return;
  const float4* xp = (const float4*)(xin + (size_t)i * CH);
  float v[CH];
#pragma unroll
  for (int q = 0; q < 8; q++) {
    float4 t = xp[q];
    v[4 * q + 0] = fmaxf(t.x * sc[4 * q + 0] + sh[4 * q + 0], 0.f);
    v[4 * q + 1] = fmaxf(t.y * sc[4 * q + 1] + sh[4 * q + 1], 0.f);
    v[4 * q + 2] = fmaxf(t.z * sc[4 * q + 2] + sh[4 * q + 2], 0.f);
    v[4 * q + 3] = fmaxf(t.w * sc[4 * q + 3] + sh[4 * q + 3], 0.f);
  }
  float acc[CH];
#pragma unroll
  for (int j = 0; j < CH; j++) acc[j] = 0.f;
#pragma unroll
  for (int k = 0; k < CH; k++) {
    float vk = v[k];
#pragma unroll
    for (int j = 0; j < CH; j++) acc[j] += vk * W[k][j];
  }
  store_split(y_out, y_back, i, acc);
}

// ---------------------------------------------------------------------------
// B: one-direction aggregation over a compact bf16 half-array (32 B rows).
// 4 lanes per node, 4 channels (uint2) each; edge loop unrolled x4 for MLP.
// Writes out[:, chanbase:chanbase+16]; optional residual and stats (sum/sumsq
// of its own 16 channels). Grid exact: N*4 / 256 = 3125 blocks.
// ---------------------------------------------------------------------------
__global__ void __launch_bounds__(256) agg_dir_kernel(
    const unsigned short* __restrict__ y, const float* __restrict__ xres,
    float* __restrict__ out,
    const int* __restrict__ off, const int* __restrict__ csr,
    float* __restrict__ stats, int chanbase) {
  __shared__ float ssum[16], sssq[16];
  int tid = threadIdx.x;
  if (tid < 16) { ssum[tid] = 0.f; sssq[tid] = 0.f; }
  __syncthreads();
  int t = blockIdx.x * 256 + tid;
  int q = t & 3;       // 4-channel group
  int i = t >> 2;      // node
  int lo = off[i], hi = off[i + 1];
  int q4 = q * 4;
  float a0 = 0.f, a1 = 0.f, a2 = 0.f, a3 = 0.f;
  int e = lo;
  for (; e + 4 <= hi; e += 4) {
    int n0 = csr[e + 0], n1 = csr[e + 1], n2 = csr[e + 2], n3 = csr[e + 3];
    uint2 p0 = *(const uint2*)(y + (size_t)n0 * 16 + q4);
    uint2 p1 = *(const uint2*)(y + (size_t)n1 * 16 + q4);
    uint2 p2 = *(const uint2*)(y + (size_t)n2 * 16 + q4);
    uint2 p3 = *(const uint2*)(y + (size_t)n3 * 16 + q4);
    a0 += BF_LO(p0.x) + BF_LO(p1.x) + BF_LO(p2.x) + BF_LO(p3.x);
    a1 += BF_HI(p0.x) + BF_HI(p1.x) + BF_HI(p2.x) + BF_HI(p3.x);
    a2 += BF_LO(p0.y) + BF_LO(p1.y) + BF_LO(p2.y) + BF_LO(p3.y);
    a3 += BF_HI(p0.y) + BF_HI(p1.y) + BF_HI(p2.y) + BF_HI(p3.y);
  }
  for (; e < hi; e++) {
    int nb = csr[e];
    uint2 p = *(const uint2*)(y + (size_t)nb * 16 + q4);
    a0 += BF_LO(p.x); a1 += BF_HI(p.x);
    a2 += BF_LO(p.y); a3 += BF_HI(p.y);
  }
  if (xres) {
    float4 r = *(const float4*)(xres + (size_t)i * CH + chanbase + q4);
    a0 += r.x; a1 += r.y; a2 += r.z; a3 += r.w;
  }
  *(float4*)(out + (size_t)i * CH + chanbase + q4) = make_float4(a0, a1, a2, a3);
  if (stats) {
    float s0 = a0 * a0, s1 = a1 * a1, s2 = a2 * a2, s3 = a3 * a3;
#pragma unroll
    for (int o = 32; o >= 4; o >>= 1) {
      a0 += __shfl_down(a0, o); a1 += __shfl_down(a1, o);
      a2 += __shfl_down(a2, o); a3 += __shfl_down(a3, o);
      s0 += __shfl_down(s0, o); s1 += __shfl_down(s1, o);
      s2 += __shfl_down(s2, o); s3 += __shfl_down(s3, o);
    }
    if ((tid & 63) < 4) {
      atomicAdd(&ssum[q4 + 0], a0); atomicAdd(&ssum[q4 + 1], a1);
      atomicAdd(&ssum[q4 + 2], a2); atomicAdd(&ssum[q4 + 3], a3);
      atomicAdd(&sssq[q4 + 0], s0); atomicAdd(&sssq[q4 + 1], s1);
      atomicAdd(&sssq[q4 + 2], s2); atomicAdd(&sssq[q4 + 3], s3);
    }
    __syncthreads();
    if (tid < 16) {
      atomicAdd(&stats[chanbase + tid], ssum[tid]);
      atomicAdd(&stats[CH + chanbase + tid], sssq[tid]);
    }
  }
}

// ---------------------------------------------------------------------------
// MLP head (x stays fp32)
// ---------------------------------------------------------------------------
__global__ void __launch_bounds__(256) score_kernel(
    const float* __restrict__ x, const int* __restrict__ indices,
    const int* __restrict__ assignment,
    const float* __restrict__ wh, const float* __restrict__ bh,
    const float* __restrict__ wo, const float* __restrict__ bo,
    float* __restrict__ s, int* __restrict__ seg) {
  __shared__ __align__(16) float s_wh[256][36];
  __shared__ float s_wo[256];
  __shared__ float s_bh[256];
  int tid = threadIdx.x;
  int m = blockIdx.x * 256 + tid;
  bool valid = m < M_SEL;
  float a[CH];
  int idx = 0;
  if (valid) {
    idx = indices[m];
    const float4* xp = (const float4*)(x + (size_t)idx * CH);
#pragma unroll
    for (int q = 0; q < 8; q++) {
      float4 t = xp[q];
      a[4 * q + 0] = fmaxf(t.x, 0.f); a[4 * q + 1] = fmaxf(t.y, 0.f);
      a[4 * q + 2] = fmaxf(t.z, 0.f); a[4 * q + 3] = fmaxf(t.w, 0.f);
    }
  }
  float sacc = 0.f;
  for (int t0 = 0; t0 < HID; t0 += 256) {
    for (int u = tid; u < CH * 256; u += 256) {
      int k = u >> 8, jj = u & 255;
      s_wh[jj][k] = wh[(size_t)k * HID + t0 + jj];
    }
    s_wo[tid] = wo[t0 + tid];
    s_bh[tid] = bh[t0 + tid];
    __syncthreads();
    if (valid) {
      for (int jj = 0; jj < 256; jj++) {
        float h = s_bh[jj];
        const float4* wp = (const float4*)&s_wh[jj][0];
#pragma unroll
        for (int q = 0; q < 8; q++) {
          float4 w = wp[q];
          h += a[4 * q] * w.x + a[4 * q + 1] * w.y + a[4 * q + 2] * w.z + a[4 * q + 3] * w.w;
        }
        sacc += fmaxf(h, 0.f) * s_wo[jj];
      }
    }
    __syncthreads();
  }
  if (valid) {
    s[m] = sacc + bo[0];
    seg[m] = assignment[idx];
  }
}

// ---------------------------------------------------------------------------
// Segmented log-softmax (seg sorted; one block per segment)
// ---------------------------------------------------------------------------
__device__ __forceinline__ int lower_bound_dev(const int* a, int n, int key) {
  int lo = 0, hi = n;
  while (lo < hi) { int mid = (lo + hi) >> 1; if (a[mid] < key) lo = mid + 1; else hi = mid; }
  return lo;
}

__global__ void __launch_bounds__(256) logsoftmax_kernel(
    const float* __restrict__ s, const int* __restrict__ seg, float* __restrict__ out) {
  __shared__ float red[256];
  __shared__ int bounds[2];
  int tid = threadIdx.x;
  int b = blockIdx.x;
  if (tid == 0) {
    bounds[0] = lower_bound_dev(seg, M_SEL, b);
    bounds[1] = lower_bound_dev(seg, M_SEL, b + 1);
  }
  __syncthreads();
  int lo = bounds[0], hi = bounds[1];
  float mx = -INFINITY;
  for (int i = lo + tid; i < hi; i += 256) mx = fmaxf(mx, s[i]);
  red[tid] = mx; __syncthreads();
  for (int o = 128; o > 0; o >>= 1) { if (tid < o) red[tid] = fmaxf(red[tid], red[tid + o]); __syncthreads(); }
  float mxv = red[0];
  __syncthreads();
  float sum = 0.f;
  for (int i = lo + tid; i < hi; i += 256) sum += expf(s[i] - mxv);
  red[tid] = sum; __syncthreads();
  for (int o = 128; o > 0; o >>= 1) { if (tid < o) red[tid] += red[tid + o]; __syncthreads(); }
  float lse = logf(red[0]);
  for (int i = lo + tid; i < hi; i += 256) out[i] = (s[i] - mxv) - lse;
}

// ---------------------------------------------------------------------------
extern "C" void kernel_launch(void* const* d_in, const int* in_sizes, int n_in,
                              void* d_out, int out_size, void* d_ws, size_t ws_size,
                              hipStream_t stream) {
  const int*   assignment = (const int*)d_in[1];
  const int*   nodes      = (const int*)d_in[2];
  const int*   src        = (const int*)d_in[3];
  const int*   dst        = (const int*)d_in[4];
  const int*   indices    = (const int*)d_in[5];
  const float* emb        = (const float*)d_in[6];
  const float* w0_out     = (const float*)d_in[7];
  const float* w0_back    = (const float*)d_in[8];
  const float* bn1_gamma  = (const float*)d_in[9];
  const float* bn1_beta   = (const float*)d_in[10];
  const float* w1_out     = (const float*)d_in[11];
  const float* w1_back    = (const float*)d_in[12];
  const float* bn2_gamma  = (const float*)d_in[13];
  const float* bn2_beta   = (const float*)d_in[14];
  const float* w2_out     = (const float*)d_in[15];
  const float* w2_back    = (const float*)d_in[16];
  const float* wh         = (const float*)d_in[17];
  const float* bh         = (const float*)d_in[18];
  const float* wo         = (const float*)d_in[19];
  const float* bo         = (const float*)d_in[20];
  float* out = (float*)d_out;

  char* ws = (char*)d_ws;
  size_t off = 0;
  auto alloc = [&](size_t bytes) {
    char* p = ws + off;
    off = (off + bytes + 255) & ~(size_t)255;
    return p;
  };
  int* deg_in  = (int*)alloc((size_t)2 * N_NODES * 4); int* deg_out = deg_in + N_NODES;
  int* cur_in  = (int*)alloc((size_t)2 * N_NODES * 4); int* cur_out = cur_in + N_NODES;
  int* off_in  = (int*)alloc((size_t)(N_NODES + 1) * 4);
  int* off_out = (int*)alloc((size_t)(N_NODES + 1) * 4);
  float* stats = (float*)alloc((size_t)16 * 64 * 4);
  int* csr_in  = (int*)alloc((size_t)N_EDGES * 4);
  int* csr_out = (int*)alloc((size_t)N_EDGES * 4);
  unsigned short* y_out  = (unsigned short*)alloc((size_t)N_NODES * 16 * 2);
  unsigned short* y_back = (unsigned short*)alloc((size_t)N_NODES * 16 * 2);
  float* xb = (float*)alloc((size_t)N_NODES * CH * 4);
  float* hb = (float*)alloc((size_t)N_NODES * CH * 4);
  float* sb = (float*)alloc((size_t)M_SEL * 4);
  int* segb = (int*)alloc((size_t)M_SEL * 4);

  hipMemsetAsync(deg_in, 0, (size_t)2 * N_NODES * 4, stream);
  hipMemsetAsync(stats, 0, (size_t)16 * 64 * 4, stream);

  hist_kernel<<<N_EDGES / 256, 256, 0, stream>>>(src, dst, deg_in, deg_out);
  scan_kernel<<<2, 1024, 0, stream>>>(deg_in, off_in, cur_in, deg_out, off_out, cur_out);
  scatter_kernel<<<N_EDGES / 256, 256, 0, stream>>>(src, dst, cur_in, cur_out, csr_in, csr_out);

  const int gA = (N_NODES + 255) / 256;
  const int gB = (N_NODES * 4) / 256;  // 3125 blocks, exact
  emb_mm_kernel<<<gA, 256, 0, stream>>>(nodes, emb, w0_out, w0_back, y_out, y_back);
  agg_dir_kernel<<<gB, 256, 0, stream>>>(y_out, nullptr, xb, off_in, csr_in, stats + 0 * 64, 0);
  agg_dir_kernel<<<gB, 256, 0, stream>>>(y_back, nullptr, xb, off_out, csr_out, stats + 0 * 64, 16);
  for (int l = 0; l < NL; l++) {
    bn_relu_mm_kernel<<<gA, 256, 0, stream>>>(xb, stats + (2 * l) * 64,
                                              bn1_gamma + l * CH, bn1_beta + l * CH,
                                              w1_out + l * CH * 16, w1_back + l * CH * 16,
                                              y_out, y_back);
    agg_dir_kernel<<<gB, 256, 0, stream>>>(y_out, nullptr, hb, off_in, csr_in,
                                           stats + (2 * l + 1) * 64, 0);
    agg_dir_kernel<<<gB, 256, 0, stream>>>(y_back, nullptr, hb, off_out, csr_out,
                                           stats + (2 * l + 1) * 64, 16);
    bn_relu_mm_kernel<<<gA, 256, 0, stream>>>(hb, stats + (2 * l + 1) * 64,
                                              bn2_gamma + l * CH, bn2_beta + l * CH,
                                              w2_out + l * CH * 16, w2_back + l * CH * 16,
                                              y_out, y_back);
    float* st = (l < NL - 1) ? (stats + (2 * l + 2) * 64) : nullptr;
    agg_dir_kernel<<<gB, 256, 0, stream>>>(y_out, xb, xb, off_in, csr_in, st, 0);
    agg_dir_kernel<<<gB, 256, 0, stream>>>(y_back, xb, xb, off_out, csr_out, st, 16);
  }
  score_kernel<<<(M_SEL + 255) / 256, 256, 0, stream>>>(xb, indices, assignment,
                                                        wh, bh, wo, bo, sb, segb);
  logsoftmax_kernel<<<NEX, 256, 0, stream>>>(sb, segb, out);
}

// Round 5
// 3111.652 us; speedup vs baseline: 1.4972x; 1.2675x over previous
//
#include <hip/hip_runtime.h>
#include <math.h>

#define N_NODES 200000
#define N_EDGES 3200000
#define M_SEL   100000
#define NEX     32
#define NT      11
#define CH      32
#define HID     1024
#define NL      8
#define BN_EPS  1e-5f

#define BSHIFT  9
#define BSIZE   512                      // nodes per bucket
#define KB      391                      // ceil(200000/512)
#define PAYMASK 0x3FFFF                  // 18-bit payload (node id < 2^18)

// bf16 helpers (RNE)
__device__ __forceinline__ unsigned bf16_bits(float f) {
  unsigned u = __float_as_uint(f);
  return (u + 0x7fffu + ((u >> 16) & 1u)) >> 16;
}
__device__ __forceinline__ unsigned pack_bf2(float lo, float hi) {
  return bf16_bits(lo) | (bf16_bits(hi) << 16);
}
#define BF_LO(u) __uint_as_float((u) << 16)
#define BF_HI(u) __uint_as_float((u) & 0xffff0000u)

// ---------------------------------------------------------------------------
// CSR build, radix-partition style.
// Phase 1: per-bucket edge counts (LDS hist -> global atomics)
// ---------------------------------------------------------------------------
__global__ void __launch_bounds__(256) bin_count_kernel(
    const int* __restrict__ src, const int* __restrict__ dst,
    int* __restrict__ bcnt_in, int* __restrict__ bcnt_out) {
  __shared__ int h_in[KB], h_out[KB];
  int tid = threadIdx.x;
  for (int i = tid; i < KB; i += 256) { h_in[i] = 0; h_out[i] = 0; }
  __syncthreads();
  for (int e = blockIdx.x * 256 + tid; e < N_EDGES; e += gridDim.x * 256) {
    atomicAdd(&h_in[dst[e] >> BSHIFT], 1);
    atomicAdd(&h_out[src[e] >> BSHIFT], 1);
  }
  __syncthreads();
  for (int b = tid; b < KB; b += 256) {
    if (h_in[b])  atomicAdd(&bcnt_in[b], h_in[b]);
    if (h_out[b]) atomicAdd(&bcnt_out[b], h_out[b]);
  }
}

// Phase 2: exclusive scan of bucket counts (one block, 256 threads, 512 slots)
__global__ void __launch_bounds__(256) bucket_scan_kernel(
    const int* __restrict__ bcnt_in, int* __restrict__ boff_in, int* __restrict__ gcur_in,
    const int* __restrict__ bcnt_out, int* __restrict__ boff_out, int* __restrict__ gcur_out) {
  __shared__ int s[512];
  __shared__ int wtot[4];
  int tid = threadIdx.x;
  int lane = tid & 63, wid = tid >> 6;
  for (int dir = 0; dir < 2; dir++) {
    const int* bcnt = dir ? bcnt_out : bcnt_in;
    int* boff = dir ? boff_out : boff_in;
    int* gcur = dir ? gcur_out : gcur_in;
    int i0 = 2 * tid, i1 = 2 * tid + 1;
    int a0 = (i0 < KB) ? bcnt[i0] : 0;
    int a1 = (i1 < KB) ? bcnt[i1] : 0;
    int pair = a0 + a1;
    int incl = pair;
#pragma unroll
    for (int o = 1; o < 64; o <<= 1) { int t = __shfl_up(incl, o); if (lane >= o) incl += t; }
    if (lane == 63) wtot[wid] = incl;
    __syncthreads();
    if (tid == 0) { int r = 0; for (int w = 0; w < 4; w++) { int v = wtot[w]; wtot[w] = r; r += v; } }
    __syncthreads();
    int exclp = incl - pair + wtot[wid];
    s[i0] = exclp;
    s[i1] = exclp + a0;
    __syncthreads();
    for (int b = tid; b < KB; b += 256) { boff[b] = s[b]; gcur[b] = s[b]; }
    if (i0 == KB - 1) boff[KB] = s[i0] + a0;      // total
    if (i1 == KB - 1) boff[KB] = s[i1] + a1;
    __syncthreads();
  }
}

// Phase 3: partition edges into per-bucket staging segments.
// record = (local_node << 18) | payload_node.  grid (ceil(E/4096), 2)
__global__ void __launch_bounds__(256) stage_kernel(
    const int* __restrict__ src, const int* __restrict__ dst,
    int* __restrict__ gcur_in, unsigned* __restrict__ staging_in,
    int* __restrict__ gcur_out, unsigned* __restrict__ staging_out) {
  __shared__ int cnt[KB], cur[KB];
  int tid = threadIdx.x;
  int dir = blockIdx.y;
  const int* key = dir ? src : dst;
  const int* pay = dir ? dst : src;
  int* gcur = dir ? gcur_out : gcur_in;
  unsigned* staging = dir ? staging_out : staging_in;
  for (int i = tid; i < KB; i += 256) cnt[i] = 0;
  __syncthreads();
  int e0 = blockIdx.x * 4096;
#pragma unroll
  for (int j = 0; j < 16; j++) {
    int e = e0 + j * 256 + tid;
    if (e < N_EDGES) atomicAdd(&cnt[key[e] >> BSHIFT], 1);
  }
  __syncthreads();
  for (int b = tid; b < KB; b += 256) {
    int c = cnt[b];
    cur[b] = c ? atomicAdd(&gcur[b], c) : 0;
  }
  __syncthreads();
#pragma unroll
  for (int j = 0; j < 16; j++) {
    int e = e0 + j * 256 + tid;
    if (e < N_EDGES) {
      int k = key[e];
      int b = k >> BSHIFT;
      int p = atomicAdd(&cur[b], 1);
      staging[p] = ((unsigned)(k & (BSIZE - 1)) << 18) | (unsigned)pay[e];
    }
  }
}

// Phase 4: per-bucket CSR build. grid (KB, 2); block = 256.
__global__ void __launch_bounds__(256) build_kernel(
    const unsigned* __restrict__ staging_in, const int* __restrict__ boff_in,
    int* __restrict__ off_in, int* __restrict__ csr_in,
    const unsigned* __restrict__ staging_out, const int* __restrict__ boff_out,
    int* __restrict__ off_out, int* __restrict__ csr_out) {
  __shared__ int cnt[BSIZE];
  __shared__ int wtot[4];
  int tid = threadIdx.x;
  int b = blockIdx.x;
  int dir = blockIdx.y;
  const unsigned* staging = dir ? staging_out : staging_in;
  const int* boff = dir ? boff_out : boff_in;
  int* off = dir ? off_out : off_in;
  int* csr = dir ? csr_out : csr_in;
  int ebase = boff[b], eend = boff[b + 1];
  int node_base = b << BSHIFT;
  int nnodes = min(BSIZE, N_NODES - node_base);
  cnt[2 * tid] = 0; cnt[2 * tid + 1] = 0;
  __syncthreads();
  for (int e = ebase + tid; e < eend; e += 256)
    atomicAdd(&cnt[staging[e] >> 18], 1);
  __syncthreads();
  int i0 = 2 * tid, i1 = 2 * tid + 1;
  int a0 = cnt[i0], a1 = cnt[i1];
  int pair = a0 + a1;
  int lane = tid & 63, wid = tid >> 6;
  int incl = pair;
#pragma unroll
  for (int o = 1; o < 64; o <<= 1) { int t = __shfl_up(incl, o); if (lane >= o) incl += t; }
  if (lane == 63) wtot[wid] = incl;
  __syncthreads();
  if (tid == 0) { int r = 0; for (int w = 0; w < 4; w++) { int v = wtot[w]; wtot[w] = r; r += v; } }
  __syncthreads();
  int exclp = incl - pair + wtot[wid];
  cnt[i0] = exclp;
  cnt[i1] = exclp + a0;
  __syncthreads();
  for (int i = tid; i < nnodes; i += 256) off[node_base + i] = ebase + cnt[i];
  if (b == KB - 1 && tid == 0) off[N_NODES] = boff[KB];
  __syncthreads();
  for (int e = ebase + tid; e < eend; e += 256) {
    unsigned rec = staging[e];
    int p = atomicAdd(&cnt[rec >> 18], 1);
    csr[ebase + p] = (int)(rec & PAYMASK);
  }
}

// ---------------------------------------------------------------------------
// Pack 32 fp32 acc channels into split bf16 arrays (16 ch each, 32 B rows)
// ---------------------------------------------------------------------------
__device__ __forceinline__ void store_split(unsigned short* y_out,
                                            unsigned short* y_back,
                                            int i, const float* acc) {
  uint4 t0, t1;
  t0.x = pack_bf2(acc[0], acc[1]);   t0.y = pack_bf2(acc[2], acc[3]);
  t0.z = pack_bf2(acc[4], acc[5]);   t0.w = pack_bf2(acc[6], acc[7]);
  t1.x = pack_bf2(acc[8], acc[9]);   t1.y = pack_bf2(acc[10], acc[11]);
  t1.z = pack_bf2(acc[12], acc[13]); t1.w = pack_bf2(acc[14], acc[15]);
  uint4* po = (uint4*)(y_out + (size_t)i * 16);
  po[0] = t0; po[1] = t1;
  t0.x = pack_bf2(acc[16], acc[17]); t0.y = pack_bf2(acc[18], acc[19]);
  t0.z = pack_bf2(acc[20], acc[21]); t0.w = pack_bf2(acc[22], acc[23]);
  t1.x = pack_bf2(acc[24], acc[25]); t1.y = pack_bf2(acc[26], acc[27]);
  t1.z = pack_bf2(acc[28], acc[29]); t1.w = pack_bf2(acc[30], acc[31]);
  uint4* pb = (uint4*)(y_back + (size_t)i * 16);
  pb[0] = t0; pb[1] = t1;
}

// ---------------------------------------------------------------------------
// A0: x0 = emb[nodes]; y = x0 @ [w0_out | w0_back]  -> split bf16
// ---------------------------------------------------------------------------
__global__ void __launch_bounds__(256) emb_mm_kernel(
    const int* __restrict__ nodes, const float* __restrict__ emb,
    const float* __restrict__ w_out, const float* __restrict__ w_back,
    unsigned short* __restrict__ y_out, unsigned short* __restrict__ y_back) {
  __shared__ float W[CH][CH];
  __shared__ float Esh[NT * CH];
  int tid = threadIdx.x;
  for (int t = tid; t < CH * CH; t += blockDim.x) {
    int k = t >> 5, j = t & 31;
    W[k][j] = (j < 16) ? w_out[k * 16 + j] : w_back[k * 16 + j - 16];
  }
  for (int t = tid; t < NT * CH; t += blockDim.x) Esh[t] = emb[t];
  __syncthreads();
  int i = blockIdx.x * blockDim.x + tid;
  if (i >= N_NODES) return;
  int tn = nodes[i];
  float v[CH];
#pragma unroll
  for (int k = 0; k < CH; k++) v[k] = Esh[tn * CH + k];
  float acc[CH];
#pragma unroll
  for (int j = 0; j < CH; j++) acc[j] = 0.f;
#pragma unroll
  for (int k = 0; k < CH; k++) {
    float vk = v[k];
#pragma unroll
    for (int j = 0; j < CH; j++) acc[j] += vk * W[k][j];
  }
  store_split(y_out, y_back, i, acc);
}

// ---------------------------------------------------------------------------
// A: y = relu(bn(x; stats,g,b)) @ [w_out | w_back]  -> split bf16
// ---------------------------------------------------------------------------
__global__ void __launch_bounds__(256) bn_relu_mm_kernel(
    const float* __restrict__ xin, const float* __restrict__ stats,
    const float* __restrict__ gamma, const float* __restrict__ beta,
    const float* __restrict__ w_out, const float* __restrict__ w_back,
    unsigned short* __restrict__ y_out, unsigned short* __restrict__ y_back) {
  __shared__ float W[CH][CH];
  __shared__ float sc[CH], sh[CH];
  int tid = threadIdx.x;
  for (int t = tid; t < CH * CH; t += blockDim.x) {
    int k = t >> 5, j = t & 31;
    W[k][j] = (j < 16) ? w_out[k * 16 + j] : w_back[k * 16 + j - 16];
  }
  if (tid < CH) {
    float m  = stats[tid] * (1.0f / N_NODES);
    float s2 = stats[CH + tid] * (1.0f / N_NODES);
    float var = s2 - m * m;
    float scale = gamma[tid] * rsqrtf(var + BN_EPS);
    sc[tid] = scale;
    sh[tid] = beta[tid] - m * scale;
  }
  __syncthreads();
  int i = blockIdx.x * blockDim.x + tid;
  if (i >= N_NODES) return;
  const float4* xp = (const float4*)(xin + (size_t)i * CH);
  float v[CH];
#pragma unroll
  for (int q = 0; q < 8; q++) {
    float4 t = xp[q];
    v[4 * q + 0] = fmaxf(t.x * sc[4 * q + 0] + sh[4 * q + 0], 0.f);
    v[4 * q + 1] = fmaxf(t.y * sc[4 * q + 1] + sh[4 * q + 1], 0.f);
    v[4 * q + 2] = fmaxf(t.z * sc[4 * q + 2] + sh[4 * q + 2], 0.f);
    v[4 * q + 3] = fmaxf(t.w * sc[4 * q + 3] + sh[4 * q + 3], 0.f);
  }
  float acc[CH];
#pragma unroll
  for (int j = 0; j < CH; j++) acc[j] = 0.f;
#pragma unroll
  for (int k = 0; k < CH; k++) {
    float vk = v[k];
#pragma unroll
    for (int j = 0; j < CH; j++) acc[j] += vk * W[k][j];
  }
  store_split(y_out, y_back, i, acc);
}

// ---------------------------------------------------------------------------
// B: one-direction aggregation over compact bf16 half-array (32 B rows).
// ---------------------------------------------------------------------------
__global__ void __launch_bounds__(256) agg_dir_kernel(
    const unsigned short* __restrict__ y, const float* __restrict__ xres,
    float* __restrict__ out,
    const int* __restrict__ off, const int* __restrict__ csr,
    float* __restrict__ stats, int chanbase) {
  __shared__ float ssum[16], sssq[16];
  int tid = threadIdx.x;
  if (tid < 16) { ssum[tid] = 0.f; sssq[tid] = 0.f; }
  __syncthreads();
  int t = blockIdx.x * 256 + tid;
  int q = t & 3;       // 4-channel group
  int i = t >> 2;      // node
  int lo = off[i], hi = off[i + 1];
  int q4 = q * 4;
  float a0 = 0.f, a1 = 0.f, a2 = 0.f, a3 = 0.f;
  int e = lo;
  for (; e + 4 <= hi; e += 4) {
    int n0 = csr[e + 0], n1 = csr[e + 1], n2 = csr[e + 2], n3 = csr[e + 3];
    uint2 p0 = *(const uint2*)(y + (size_t)n0 * 16 + q4);
    uint2 p1 = *(const uint2*)(y + (size_t)n1 * 16 + q4);
    uint2 p2 = *(const uint2*)(y + (size_t)n2 * 16 + q4);
    uint2 p3 = *(const uint2*)(y + (size_t)n3 * 16 + q4);
    a0 += BF_LO(p0.x) + BF_LO(p1.x) + BF_LO(p2.x) + BF_LO(p3.x);
    a1 += BF_HI(p0.x) + BF_HI(p1.x) + BF_HI(p2.x) + BF_HI(p3.x);
    a2 += BF_LO(p0.y) + BF_LO(p1.y) + BF_LO(p2.y) + BF_LO(p3.y);
    a3 += BF_HI(p0.y) + BF_HI(p1.y) + BF_HI(p2.y) + BF_HI(p3.y);
  }
  for (; e < hi; e++) {
    int nb = csr[e];
    uint2 p = *(const uint2*)(y + (size_t)nb * 16 + q4);
    a0 += BF_LO(p.x); a1 += BF_HI(p.x);
    a2 += BF_LO(p.y); a3 += BF_HI(p.y);
  }
  if (xres) {
    float4 r = *(const float4*)(xres + (size_t)i * CH + chanbase + q4);
    a0 += r.x; a1 += r.y; a2 += r.z; a3 += r.w;
  }
  *(float4*)(out + (size_t)i * CH + chanbase + q4) = make_float4(a0, a1, a2, a3);
  if (stats) {
    float s0 = a0 * a0, s1 = a1 * a1, s2 = a2 * a2, s3 = a3 * a3;
#pragma unroll
    for (int o = 32; o >= 4; o >>= 1) {
      a0 += __shfl_down(a0, o); a1 += __shfl_down(a1, o);
      a2 += __shfl_down(a2, o); a3 += __shfl_down(a3, o);
      s0 += __shfl_down(s0, o); s1 += __shfl_down(s1, o);
      s2 += __shfl_down(s2, o); s3 += __shfl_down(s3, o);
    }
    if ((tid & 63) < 4) {
      atomicAdd(&ssum[q4 + 0], a0); atomicAdd(&ssum[q4 + 1], a1);
      atomicAdd(&ssum[q4 + 2], a2); atomicAdd(&ssum[q4 + 3], a3);
      atomicAdd(&sssq[q4 + 0], s0); atomicAdd(&sssq[q4 + 1], s1);
      atomicAdd(&sssq[q4 + 2], s2); atomicAdd(&sssq[q4 + 3], s3);
    }
    __syncthreads();
    if (tid < 16) {
      atomicAdd(&stats[chanbase + tid], ssum[tid]);
      atomicAdd(&stats[CH + chanbase + tid], sssq[tid]);
    }
  }
}

// ---------------------------------------------------------------------------
// MLP head (x stays fp32)
// ---------------------------------------------------------------------------
__global__ void __launch_bounds__(256) score_kernel(
    const float* __restrict__ x, const int* __restrict__ indices,
    const int* __restrict__ assignment,
    const float* __restrict__ wh, const float* __restrict__ bh,
    const float* __restrict__ wo, const float* __restrict__ bo,
    float* __restrict__ s, int* __restrict__ seg) {
  __shared__ __align__(16) float s_wh[256][36];
  __shared__ float s_wo[256];
  __shared__ float s_bh[256];
  int tid = threadIdx.x;
  int m = blockIdx.x * 256 + tid;
  bool valid = m < M_SEL;
  float a[CH];
  int idx = 0;
  if (valid) {
    idx = indices[m];
    const float4* xp = (const float4*)(x + (size_t)idx * CH);
#pragma unroll
    for (int q = 0; q < 8; q++) {
      float4 t = xp[q];
      a[4 * q + 0] = fmaxf(t.x, 0.f); a[4 * q + 1] = fmaxf(t.y, 0.f);
      a[4 * q + 2] = fmaxf(t.z, 0.f); a[4 * q + 3] = fmaxf(t.w, 0.f);
    }
  }
  float sacc = 0.f;
  for (int t0 = 0; t0 < HID; t0 += 256) {
    for (int u = tid; u < CH * 256; u += 256) {
      int k = u >> 8, jj = u & 255;
      s_wh[jj][k] = wh[(size_t)k * HID + t0 + jj];
    }
    s_wo[tid] = wo[t0 + tid];
    s_bh[tid] = bh[t0 + tid];
    __syncthreads();
    if (valid) {
      for (int jj = 0; jj < 256; jj++) {
        float h = s_bh[jj];
        const float4* wp = (const float4*)&s_wh[jj][0];
#pragma unroll
        for (int q = 0; q < 8; q++) {
          float4 w = wp[q];
          h += a[4 * q] * w.x + a[4 * q + 1] * w.y + a[4 * q + 2] * w.z + a[4 * q + 3] * w.w;
        }
        sacc += fmaxf(h, 0.f) * s_wo[jj];
      }
    }
    __syncthreads();
  }
  if (valid) {
    s[m] = sacc + bo[0];
    seg[m] = assignment[idx];
  }
}

// ---------------------------------------------------------------------------
// Segmented log-softmax (seg sorted; one block per segment)
// ---------------------------------------------------------------------------
__device__ __forceinline__ int lower_bound_dev(const int* a, int n, int key) {
  int lo = 0, hi = n;
  while (lo < hi) { int mid = (lo + hi) >> 1; if (a[mid] < key) lo = mid + 1; else hi = mid; }
  return lo;
}

__global__ void __launch_bounds__(256) logsoftmax_kernel(
    const float* __restrict__ s, const int* __restrict__ seg, float* __restrict__ out) {
  __shared__ float red[256];
  __shared__ int bounds[2];
  int tid = threadIdx.x;
  int b = blockIdx.x;
  if (tid == 0) {
    bounds[0] = lower_bound_dev(seg, M_SEL, b);
    bounds[1] = lower_bound_dev(seg, M_SEL, b + 1);
  }
  __syncthreads();
  int lo = bounds[0], hi = bounds[1];
  float mx = -INFINITY;
  for (int i = lo + tid; i < hi; i += 256) mx = fmaxf(mx, s[i]);
  red[tid] = mx; __syncthreads();
  for (int o = 128; o > 0; o >>= 1) { if (tid < o) red[tid] = fmaxf(red[tid], red[tid + o]); __syncthreads(); }
  float mxv = red[0];
  __syncthreads();
  float sum = 0.f;
  for (int i = lo + tid; i < hi; i += 256) sum += expf(s[i] - mxv);
  red[tid] = sum; __syncthreads();
  for (int o = 128; o > 0; o >>= 1) { if (tid < o) red[tid] += red[tid + o]; __syncthreads(); }
  float lse = logf(red[0]);
  for (int i = lo + tid; i < hi; i += 256) out[i] = (s[i] - mxv) - lse;
}

// ---------------------------------------------------------------------------
extern "C" void kernel_launch(void* const* d_in, const int* in_sizes, int n_in,
                              void* d_out, int out_size, void* d_ws, size_t ws_size,
                              hipStream_t stream) {
  const int*   assignment = (const int*)d_in[1];
  const int*   nodes      = (const int*)d_in[2];
  const int*   src        = (const int*)d_in[3];
  const int*   dst        = (const int*)d_in[4];
  const int*   indices    = (const int*)d_in[5];
  const float* emb        = (const float*)d_in[6];
  const float* w0_out     = (const float*)d_in[7];
  const float* w0_back    = (const float*)d_in[8];
  const float* bn1_gamma  = (const float*)d_in[9];
  const float* bn1_beta   = (const float*)d_in[10];
  const float* w1_out     = (const float*)d_in[11];
  const float* w1_back    = (const float*)d_in[12];
  const float* bn2_gamma  = (const float*)d_in[13];
  const float* bn2_beta   = (const float*)d_in[14];
  const float* w2_out     = (const float*)d_in[15];
  const float* w2_back    = (const float*)d_in[16];
  const float* wh         = (const float*)d_in[17];
  const float* bh         = (const float*)d_in[18];
  const float* wo         = (const float*)d_in[19];
  const float* bo         = (const float*)d_in[20];
  float* out = (float*)d_out;

  char* ws = (char*)d_ws;
  size_t off = 0;
  auto alloc = [&](size_t bytes) {
    char* p = ws + off;
    off = (off + bytes + 255) & ~(size_t)255;
    return p;
  };
  // bcnt_in/bcnt_out CONTIGUOUS in one alloc: single memset must cover both
  // (allocator pads to 256B — separate allocs would leave poison in the gap!)
  int* bcnt_in  = (int*)alloc((size_t)2 * KB * 4); int* bcnt_out = bcnt_in + KB;
  int* boff_in  = (int*)alloc((size_t)(KB + 1) * 4);
  int* boff_out = (int*)alloc((size_t)(KB + 1) * 4);
  int* gcur_in  = (int*)alloc((size_t)KB * 4);
  int* gcur_out = (int*)alloc((size_t)KB * 4);
  int* off_in   = (int*)alloc((size_t)(N_NODES + 1) * 4);
  int* off_out  = (int*)alloc((size_t)(N_NODES + 1) * 4);
  float* stats  = (float*)alloc((size_t)16 * 64 * 4);
  int* csr_in   = (int*)alloc((size_t)N_EDGES * 4);
  int* csr_out  = (int*)alloc((size_t)N_EDGES * 4);
  unsigned short* y_out  = (unsigned short*)alloc((size_t)N_NODES * 16 * 2);
  unsigned short* y_back = (unsigned short*)alloc((size_t)N_NODES * 16 * 2);
  float* xb = (float*)alloc((size_t)N_NODES * CH * 4);
  float* hb = (float*)alloc((size_t)N_NODES * CH * 4);
  float* sb = (float*)alloc((size_t)M_SEL * 4);
  int* segb = (int*)alloc((size_t)M_SEL * 4);
  // staging aliases xb (consumed by build_kernel before xb is first written)
  unsigned* staging_in  = (unsigned*)xb;
  unsigned* staging_out = (unsigned*)xb + N_EDGES;

  hipMemsetAsync(bcnt_in, 0, (size_t)2 * KB * 4, stream);
  hipMemsetAsync(stats, 0, (size_t)16 * 64 * 4, stream);

  bin_count_kernel<<<1024, 256, 0, stream>>>(src, dst, bcnt_in, bcnt_out);
  bucket_scan_kernel<<<1, 256, 0, stream>>>(bcnt_in, boff_in, gcur_in,
                                            bcnt_out, boff_out, gcur_out);
  dim3 gStage((N_EDGES + 4095) / 4096, 2);
  stage_kernel<<<gStage, 256, 0, stream>>>(src, dst, gcur_in, staging_in,
                                           gcur_out, staging_out);
  dim3 gBuild(KB, 2);
  build_kernel<<<gBuild, 256, 0, stream>>>(staging_in, boff_in, off_in, csr_in,
                                           staging_out, boff_out, off_out, csr_out);

  const int gA = (N_NODES + 255) / 256;
  const int gB = (N_NODES * 4) / 256;  // 3125 blocks, exact
  emb_mm_kernel<<<gA, 256, 0, stream>>>(nodes, emb, w0_out, w0_back, y_out, y_back);
  agg_dir_kernel<<<gB, 256, 0, stream>>>(y_out, nullptr, xb, off_in, csr_in, stats + 0 * 64, 0);
  agg_dir_kernel<<<gB, 256, 0, stream>>>(y_back, nullptr, xb, off_out, csr_out, stats + 0 * 64, 16);
  for (int l = 0; l < NL; l++) {
    bn_relu_mm_kernel<<<gA, 256, 0, stream>>>(xb, stats + (2 * l) * 64,
                                              bn1_gamma + l * CH, bn1_beta + l * CH,
                                              w1_out + l * CH * 16, w1_back + l * CH * 16,
                                              y_out, y_back);
    agg_dir_kernel<<<gB, 256, 0, stream>>>(y_out, nullptr, hb, off_in, csr_in,
                                           stats + (2 * l + 1) * 64, 0);
    agg_dir_kernel<<<gB, 256, 0, stream>>>(y_back, nullptr, hb, off_out, csr_out,
                                           stats + (2 * l + 1) * 64, 16);
    bn_relu_mm_kernel<<<gA, 256, 0, stream>>>(hb, stats + (2 * l + 1) * 64,
                                              bn2_gamma + l * CH, bn2_beta + l * CH,
                                              w2_out + l * CH * 16, w2_back + l * CH * 16,
                                              y_out, y_back);
    float* st = (l < NL - 1) ? (stats + (2 * l + 2) * 64) : nullptr;
    agg_dir_kernel<<<gB, 256, 0, stream>>>(y_out, xb, xb, off_in, csr_in, st, 0);
    agg_dir_kernel<<<gB, 256, 0, stream>>>(y_back, xb, xb, off_out, csr_out, st, 16);
  }
  score_kernel<<<(M_SEL + 255) / 256, 256, 0, stream>>>(xb, indices, assignment,
                                                        wh, bh, wo, bo, sb, segb);
  logsoftmax_kernel<<<NEX, 256, 0, stream>>>(sb, segb, out);
}